// Round 11
// baseline (394.122 us; speedup 1.0000x reference)
//
#include <hip/hip_runtime.h>
#include <hip/hip_bf16.h>
#include <stdint.h>

#define B_  4
#define T_  300
#define U_  60
#define V_  1000
#define M_TOT (B_*T_*U_)   // 72000
#define MBCNT 564          // ceil(72000/128)
#define WK  1056           // padded W1t row stride (shorts)

typedef __attribute__((ext_vector_type(8))) short short8;
typedef __attribute__((ext_vector_type(4))) float f32x4;
typedef __attribute__((ext_vector_type(4))) int int4v;

__device__ __forceinline__ short f2bf(float f) {
    union { float f; uint32_t u; } c; c.f = f;
    uint32_t u = c.u;
    uint32_t r = (u + 0x7FFFu + ((u >> 16) & 1u)) >> 16;
    return (short)r;
}

__device__ __forceinline__ float b2f(short s) {
    union { float f; uint32_t u; } c;
    c.u = ((uint32_t)(uint16_t)s) << 16;
    return c.f;
}

__device__ __forceinline__ float fast_tanh(float x) {
    float e = __expf(2.0f * x);
    float r = __builtin_amdgcn_rcpf(e + 1.0f);
    return 1.0f - 2.0f * r;
}

__device__ __forceinline__ void gl_lds16(const void* g, void* l) {
    __builtin_amdgcn_global_load_lds(
        (const __attribute__((address_space(1))) void*)g,
        (__attribute__((address_space(3))) void*)l, 16, 0, 0);
}

// ---------------- prep kernels ----------------

// fp32 [R][C] -> bf16 [C][R] with row stride ostride (used for W1)
__global__ void transpose_cvt(const float* __restrict__ in, short* __restrict__ out,
                              int R, int C, int ostride) {
    __shared__ float tile[64][65];
    const int tx = threadIdx.x & 63, ty = threadIdx.x >> 6;
    const int r0 = blockIdx.y * 64, c0 = blockIdx.x * 64;
#pragma unroll
    for (int i = 0; i < 16; ++i) {
        int r = r0 + i * 4 + ty, c = c0 + tx;
        float v = 0.f;
        if (r < R && c < C) v = in[(long)r * C + c];
        tile[i * 4 + ty][tx] = v;
    }
    __syncthreads();
#pragma unroll
    for (int i = 0; i < 16; ++i) {
        int oc = c0 + i * 4 + ty;
        int orr = r0 + tx;
        out[(long)oc * ostride + orr] = f2bf(tile[tx][i * 4 + ty]);
    }
}

// W2 [1024 k][1000 v] -> half-tile units: unit(nb,t,h)=((nb*16+t)*2+h) of
// 128 v-rows x 64 k (16KB), plain row-major within unit.
__global__ void transpose_pack_w2(const float* __restrict__ in, short* __restrict__ out) {
    __shared__ float tile[64][65];
    const int tx = threadIdx.x & 63, ty = threadIdx.x >> 6;
    const int r0 = blockIdx.y * 64, c0 = blockIdx.x * 64;   // r=k, c=v
#pragma unroll
    for (int i = 0; i < 16; ++i) {
        int r = r0 + i * 4 + ty, c = c0 + tx;
        float v = 0.f;
        if (c < V_) v = in[(long)r * V_ + c];
        tile[i * 4 + ty][tx] = v;
    }
    __syncthreads();
#pragma unroll
    for (int i = 0; i < 16; ++i) {
        int oc = c0 + i * 4 + ty;       // v 0..1023
        int orr = r0 + tx;              // k 0..1023
        int nb = oc >> 8, pr = oc & 255, h = pr >> 7, rr = pr & 127;
        int t = orr >> 6, kk = orr & 63;
        out[(long)((nb * 16 + t) * 2 + h) * 8192 + rr * 64 + kk] =
            f2bf(tile[tx][i * 4 + ty]);
    }
}

// P(bf16)[M][1024] = bf16(X[M][512]) @ W1t[k_off:k_off+512]^T (+ b1)
__global__ __launch_bounds__(256, 2) void proj_gemm(
        const float* __restrict__ X, int M, int k_off,
        const short* __restrict__ Wt,
        const float* __restrict__ b1,
        short* __restrict__ P)
{
    __shared__ short As[64 * 64];
    const int tid = threadIdx.x;
    const int lane = tid & 63;
    const int w = tid >> 6;
    const int wm = w >> 1, wn = w & 1;
    const int m0 = blockIdx.x * 64, n0 = blockIdx.y * 64;

    f32x4 acc[2][2] = {};
    for (int k0 = 0; k0 < 512; k0 += 64) {
#pragma unroll
        for (int c = 0; c < 2; ++c) {
            int lin = tid + 256 * c;
            int row = lin >> 3, k8 = lin & 7;
            int m = m0 + row;
            short vals[8];
            if (m < M) {
                const float* xp = X + (long)m * 512 + k0 + k8 * 8;
#pragma unroll
                for (int j = 0; j < 8; ++j) vals[j] = f2bf(xp[j]);
            } else {
#pragma unroll
                for (int j = 0; j < 8; ++j) vals[j] = 0;
            }
            int byte = row * 128 + k8 * 16;
            byte ^= (row & 7) << 4;
            *(int4v*)((char*)As + byte) = *(const int4v*)vals;
        }
        __syncthreads();
#pragma unroll
        for (int ks = 0; ks < 2; ++ks) {
            short8 af[2];
#pragma unroll
            for (int mf = 0; mf < 2; ++mf) {
                int row = wm * 32 + mf * 16 + (lane & 15);
                int byte = row * 128 + ks * 64 + (lane >> 4) * 16;
                byte ^= (row & 7) << 4;
                af[mf] = *(const short8*)((char*)As + byte);
            }
#pragma unroll
            for (int nf = 0; nf < 2; ++nf) {
                int h = n0 + wn * 32 + nf * 16 + (lane & 15);
                const short* bp = Wt + (long)h * WK + k_off + k0 + ks * 32 + (lane >> 4) * 8;
                short8 bfv = *(const short8*)bp;
#pragma unroll
                for (int mf = 0; mf < 2; ++mf)
                    acc[mf][nf] = __builtin_amdgcn_mfma_f32_16x16x32_bf16(af[mf], bfv, acc[mf][nf], 0, 0, 0);
            }
        }
        __syncthreads();
    }
#pragma unroll
    for (int mf = 0; mf < 2; ++mf)
#pragma unroll
        for (int nf = 0; nf < 2; ++nf) {
            int h = n0 + wn * 32 + nf * 16 + (lane & 15);
            float bb = b1 ? b1[h] : 0.f;
#pragma unroll
            for (int j = 0; j < 4; ++j) {
                int m = m0 + wm * 32 + mf * 16 + (lane >> 4) * 4 + j;
                if (m < M) P[(long)m * 1024 + h] = f2bf(acc[mf][nf][j] + bb);
            }
        }
}

// ---------------- fused GEMM: out = tanh(encB+decB) @ W2p^T + b2 ------------
// BM=128, BN=256, BK=64, 8 waves (2m x 4n), wave tile 64x64 (acc 64 AGPR).
// LDS per dbuf: A 16KB (VALU-generated tanh, XOR-swizzled ds_write) +
// B 32KB (gl_lds staged, pre-permuted source) = 96KB total.
// Per K-tile: 2 phases x 16 MFMA; e/d loads issued BEFORE ST_B so the
// AGEN dep-wait retires them without draining B(t+1) (vmcnt is in-order).
// Counted gate vmcnt(8) once per tile; drain only at the final tile.
__global__ __launch_bounds__(512, 2) void gemm_fused(
        const short* __restrict__ encB,  // [1200][1024] bf16
        const short* __restrict__ decB,  // [240][1024] bf16 (b1 folded)
        const short* __restrict__ W2p,   // units (nb,t,h) 128x64
        const float* __restrict__ b2,
        float* __restrict__ out)         // [M_TOT][V_] fp32
{
    __shared__ __align__(16) char lds[2 * 49152];

    const int tid = threadIdx.x;
    const int lane = tid & 63;
    const int w = tid >> 6;
    const int wm = w >> 2, wn = w & 3;
    const int l15 = lane & 15, ksel = lane >> 4;

    // bijective XCD swizzle (nwg = 2256 = 8*282)
    const int nwg = gridDim.x;
    int bid = blockIdx.x;
    int q = nwg >> 3, r = nwg & 7;
    int xcd = bid & 7, lq = bid >> 3;
    int wg = (xcd < r ? xcd * (q + 1) : r * (q + 1) + (xcd - r) * q) + lq;
    const int mb = wg >> 2, nb = wg & 3;

    // ---- B staging (source granule permuted g = (tid&7)^(row&7)) ----
    const int rowA = tid >> 3;
    const int gA = (tid & 7) ^ (rowA & 7);
    const short* bSrc = W2p + (long)nb * 262144 + rowA * 64 + gA * 8;
    const int wq = w << 10;

    // ---- A-gen assignment: thread -> one m-row, 16 k-elems/tile ----
    const int ar = tid >> 2;            // 0..127
    const int g0 = (tid & 3) * 2;       // first of two 8-elem granules
    const short* eP; const short* dP;
    {
        int m = mb * 128 + ar;
        if (m >= M_TOT) m = M_TOT - 1;  // tail rows duplicate; stores masked
        int bt = m / U_;
        int b = m / (T_ * U_);
        int uu = m - bt * U_;
        int kc = (tid & 3) * 16;
        eP = encB + (long)bt * 1024 + kc;
        dP = decB + (long)(b * U_ + uu) * 1024 + kc;
    }
    const int agb0 = ar * 128 + ((g0 ^ (ar & 7)) << 4);
    const int agb1 = ar * 128 + (((g0 + 1) ^ (ar & 7)) << 4);

    short8 ea, eb, da, db;              // e/d staging (16 VGPR)
    short8 af[4], bf[4];
    f32x4 acc[4][4] = {};

#define EDLOAD(tt_) do { const int ko_ = (tt_) * 64;                         \
    ea = *(const short8*)(eP + ko_); eb = *(const short8*)(eP + ko_ + 8);    \
    da = *(const short8*)(dP + ko_); db = *(const short8*)(dP + ko_ + 8);    \
} while (0)

#define ST_B(uidx_, roff_) do {                                              \
    gl_lds16(bSrc + (long)(uidx_) * 8192, (char*)lds + (roff_) + wq);        \
    gl_lds16(bSrc + (long)(uidx_) * 8192 + 4096,                             \
             (char*)lds + (roff_) + 8192 + wq);                              \
} while (0)

#define AGEN(nxt_) do {                                                      \
    short vv_[8];                                                            \
    char* dst_ = (char*)lds + (nxt_) * 49152;                                \
    _Pragma("unroll")                                                        \
    for (int j = 0; j < 8; ++j)                                              \
        vv_[j] = f2bf(fast_tanh(b2f(ea[j]) + b2f(da[j])));                   \
    *(int4v*)(dst_ + agb0) = *(const int4v*)vv_;                             \
    _Pragma("unroll")                                                        \
    for (int j = 0; j < 8; ++j)                                              \
        vv_[j] = f2bf(fast_tanh(b2f(eb[j]) + b2f(db[j])));                   \
    *(int4v*)(dst_ + agb1) = *(const int4v*)vv_;                             \
} while (0)

#define RD_AF(d_, kh_) do {                                                  \
    _Pragma("unroll")                                                        \
    for (int mf = 0; mf < 4; ++mf) {                                         \
        const int rw_ = wm * 64 + mf * 16 + l15;                             \
        af[mf] = *(const short8*)((const char*)lds + (d_) * 49152            \
            + rw_ * 128 + ((((kh_) * 4 + ksel) ^ (rw_ & 7)) << 4));          \
    } } while (0)

#define RD_BF(d_, kh_) do {                                                  \
    _Pragma("unroll")                                                        \
    for (int nf = 0; nf < 4; ++nf) {                                         \
        const int rw_ = wn * 64 + nf * 16 + l15;                             \
        bf[nf] = *(const short8*)((const char*)lds + (d_) * 49152 + 16384    \
            + (rw_ >> 7) * 16384 + (rw_ & 127) * 128                         \
            + ((((kh_) * 4 + ksel) ^ (rw_ & 7)) << 4));                      \
    } } while (0)

#define MM16 do {                                                            \
    __builtin_amdgcn_s_setprio(1);                                           \
    _Pragma("unroll")                                                        \
    for (int nf = 0; nf < 4; ++nf)                                           \
        _Pragma("unroll")                                                    \
        for (int mf = 0; mf < 4; ++mf)                                       \
            acc[mf][nf] = __builtin_amdgcn_mfma_f32_16x16x32_bf16(           \
                af[mf], bf[nf], acc[mf][nf], 0, 0, 0);                       \
    __builtin_amdgcn_s_setprio(0);                                           \
} while (0)

#define LGKM0 do {                                                           \
    asm volatile("s_waitcnt lgkmcnt(0)" ::: "memory");                       \
    __builtin_amdgcn_sched_barrier(0);                                       \
} while (0)

#define TILE(t_, cur_, nxt_, GATE_) do {                                     \
    if ((t_) < 15) {                                                         \
        EDLOAD((t_) + 1);                                                    \
        ST_B(((t_) + 1) * 2,     (nxt_) * 49152 + 16384);                    \
        ST_B(((t_) + 1) * 2 + 1, (nxt_) * 49152 + 32768);                    \
    }                                                                        \
    asm volatile("s_waitcnt vmcnt(" GATE_ ")" ::: "memory");                 \
    __builtin_amdgcn_s_barrier();                                            \
    __builtin_amdgcn_sched_barrier(0);                                       \
    RD_AF(cur_, 0); RD_BF(cur_, 0);                                          \
    LGKM0;                                                                   \
    MM16;                                                                    \
    __builtin_amdgcn_s_barrier();                                            \
    RD_AF(cur_, 1); RD_BF(cur_, 1);                                          \
    if ((t_) < 15) AGEN(nxt_);                                               \
    LGKM0;                                                                   \
    MM16;                                                                    \
    __builtin_amdgcn_s_barrier();                                            \
} while (0)

    // prologue: tile 0 -> buf0 (A by VALU, B by gl_lds); full drain once
    EDLOAD(0);
    ST_B(0, 16384);
    ST_B(1, 32768);
    AGEN(0);
    asm volatile("s_waitcnt vmcnt(0) lgkmcnt(0)" ::: "memory");
    __builtin_amdgcn_s_barrier();

#pragma unroll 1
    for (int t = 0; t < 15; ++t) {
        const int cur = t & 1;
        TILE(t, cur, cur ^ 1, "8");
    }
    TILE(15, 1, 0, "0");

    // epilogue: + b2, store fp32
#pragma unroll
    for (int nf = 0; nf < 4; ++nf) {
        int n = nb * 256 + wn * 64 + nf * 16 + l15;
        if (n < V_) {
            float bv = b2[n];
#pragma unroll
            for (int mf = 0; mf < 4; ++mf)
#pragma unroll
                for (int j = 0; j < 4; ++j) {
                    int m = mb * 128 + wm * 64 + mf * 16 + ksel * 4 + j;
                    if (m < M_TOT)
                        out[(long)m * V_ + n] = acc[mf][nf][j] + bv;
                }
        }
    }
#undef EDLOAD
#undef ST_B
#undef AGEN
#undef RD_AF
#undef RD_BF
#undef MM16
#undef LGKM0
#undef TILE
}

// ---------------- launch ----------------
extern "C" void kernel_launch(void* const* d_in, const int* in_sizes, int n_in,
                              void* d_out, int out_size, void* d_ws, size_t ws_size,
                              hipStream_t stream) {
    const float* enc = (const float*)d_in[0];
    const float* dec = (const float*)d_in[1];
    const float* W1  = (const float*)d_in[2];
    const float* b1  = (const float*)d_in[3];
    const float* W2  = (const float*)d_in[4];
    const float* b2  = (const float*)d_in[5];
    float* out = (float*)d_out;

    char* ws = (char*)d_ws;
    size_t off = 0;
    short* W1t  = (short*)(ws + off); off += (size_t)1024 * WK * 2;      // 2.06 MB
    short* W2p  = (short*)(ws + off); off += (size_t)128 * 8192 * 2;     // 2.10 MB
    short* encB = (short*)(ws + off); off += (size_t)1200 * 1024 * 2;    // 2.40 MB
    short* decB = (short*)(ws + off);                                    // 0.48 MB

    transpose_cvt<<<dim3(16, 16), 256, 0, stream>>>(W1, W1t, 1024, 1024, WK);
    transpose_pack_w2<<<dim3(16, 16), 256, 0, stream>>>(W2, W2p);
    proj_gemm<<<dim3(19, 16), 256, 0, stream>>>(enc, 1200, 0,   W1t, nullptr, encB);
    proj_gemm<<<dim3(4, 16),  256, 0, stream>>>(dec, 240,  512, W1t, b1,      decB);

    gemm_fused<<<MBCNT * 4, 512, 0, stream>>>(encB, decB, W2p, b2, out);
}

// Round 12
// 351.470 us; speedup vs baseline: 1.1214x; 1.1214x over previous
//
#include <hip/hip_runtime.h>
#include <hip/hip_bf16.h>
#include <stdint.h>

#define B_  4
#define T_  300
#define U_  60
#define V_  1000
#define M_TOT (B_*T_*U_)   // 72000
#define MBCNT 282          // ceil(72000/256)
#define NT  32             // K-tiles (K=1024, BK=32)
#define WK  1056           // padded W1t row stride (shorts)

typedef __attribute__((ext_vector_type(8))) short short8;
typedef __attribute__((ext_vector_type(4))) float f32x4;
typedef __attribute__((ext_vector_type(4))) int int4v;

__device__ __forceinline__ short f2bf(float f) {
    union { float f; uint32_t u; } c; c.f = f;
    uint32_t u = c.u;
    uint32_t r = (u + 0x7FFFu + ((u >> 16) & 1u)) >> 16;
    return (short)r;
}

__device__ __forceinline__ float b2f(short s) {
    union { float f; uint32_t u; } c;
    c.u = ((uint32_t)(uint16_t)s) << 16;
    return c.f;
}

__device__ __forceinline__ float fast_tanh(float x) {
    float e = __expf(2.0f * x);
    float r = __builtin_amdgcn_rcpf(e + 1.0f);
    return 1.0f - 2.0f * r;
}

__device__ __forceinline__ void gl_lds16(const void* g, void* l) {
    __builtin_amdgcn_global_load_lds(
        (const __attribute__((address_space(1))) void*)g,
        (__attribute__((address_space(3))) void*)l, 16, 0, 0);
}

// ---------------- prep kernels ----------------

// fp32 [R][C] -> bf16 [C][R] with row stride ostride (used for W1)
__global__ void transpose_cvt(const float* __restrict__ in, short* __restrict__ out,
                              int R, int C, int ostride) {
    __shared__ float tile[64][65];
    const int tx = threadIdx.x & 63, ty = threadIdx.x >> 6;
    const int r0 = blockIdx.y * 64, c0 = blockIdx.x * 64;
#pragma unroll
    for (int i = 0; i < 16; ++i) {
        int r = r0 + i * 4 + ty, c = c0 + tx;
        float v = 0.f;
        if (r < R && c < C) v = in[(long)r * C + c];
        tile[i * 4 + ty][tx] = v;
    }
    __syncthreads();
#pragma unroll
    for (int i = 0; i < 16; ++i) {
        int oc = c0 + i * 4 + ty;
        int orr = r0 + tx;
        out[(long)oc * ostride + orr] = f2bf(tile[tx][i * 4 + ty]);
    }
}

// W2 [1024 k][1000 v] -> units (nb,t): 256 v-rows x 32 k (16KB), row-major.
__global__ void transpose_pack_w2(const float* __restrict__ in, short* __restrict__ out) {
    __shared__ float tile[64][65];
    const int tx = threadIdx.x & 63, ty = threadIdx.x >> 6;
    const int r0 = blockIdx.y * 64, c0 = blockIdx.x * 64;   // r=k, c=v
#pragma unroll
    for (int i = 0; i < 16; ++i) {
        int r = r0 + i * 4 + ty, c = c0 + tx;
        float v = 0.f;
        if (c < V_) v = in[(long)r * V_ + c];
        tile[i * 4 + ty][tx] = v;
    }
    __syncthreads();
#pragma unroll
    for (int i = 0; i < 16; ++i) {
        int oc = c0 + i * 4 + ty;       // v 0..1023
        int orr = r0 + tx;              // k 0..1023
        int nb = oc >> 8, rr = oc & 255;
        int t = orr >> 5, kk = orr & 31;
        out[(long)(nb * 32 + t) * 8192 + rr * 32 + kk] = f2bf(tile[tx][i * 4 + ty]);
    }
}

// P(bf16)[M][1024] = bf16(X[M][512]) @ W1t[k_off:k_off+512]^T (+ b1)
__global__ __launch_bounds__(256, 2) void proj_gemm(
        const float* __restrict__ X, int M, int k_off,
        const short* __restrict__ Wt,
        const float* __restrict__ b1,
        short* __restrict__ P)
{
    __shared__ short As[64 * 64];
    const int tid = threadIdx.x;
    const int lane = tid & 63;
    const int w = tid >> 6;
    const int wm = w >> 1, wn = w & 1;
    const int m0 = blockIdx.x * 64, n0 = blockIdx.y * 64;

    f32x4 acc[2][2] = {};
    for (int k0 = 0; k0 < 512; k0 += 64) {
#pragma unroll
        for (int c = 0; c < 2; ++c) {
            int lin = tid + 256 * c;
            int row = lin >> 3, k8 = lin & 7;
            int m = m0 + row;
            short vals[8];
            if (m < M) {
                const float* xp = X + (long)m * 512 + k0 + k8 * 8;
#pragma unroll
                for (int j = 0; j < 8; ++j) vals[j] = f2bf(xp[j]);
            } else {
#pragma unroll
                for (int j = 0; j < 8; ++j) vals[j] = 0;
            }
            int byte = row * 128 + k8 * 16;
            byte ^= (row & 7) << 4;
            *(int4v*)((char*)As + byte) = *(const int4v*)vals;
        }
        __syncthreads();
#pragma unroll
        for (int ks = 0; ks < 2; ++ks) {
            short8 af[2];
#pragma unroll
            for (int mf = 0; mf < 2; ++mf) {
                int row = wm * 32 + mf * 16 + (lane & 15);
                int byte = row * 128 + ks * 64 + (lane >> 4) * 16;
                byte ^= (row & 7) << 4;
                af[mf] = *(const short8*)((char*)As + byte);
            }
#pragma unroll
            for (int nf = 0; nf < 2; ++nf) {
                int h = n0 + wn * 32 + nf * 16 + (lane & 15);
                const short* bp = Wt + (long)h * WK + k_off + k0 + ks * 32 + (lane >> 4) * 8;
                short8 bfv = *(const short8*)bp;
#pragma unroll
                for (int mf = 0; mf < 2; ++mf)
                    acc[mf][nf] = __builtin_amdgcn_mfma_f32_16x16x32_bf16(af[mf], bfv, acc[mf][nf], 0, 0, 0);
            }
        }
        __syncthreads();
    }
#pragma unroll
    for (int mf = 0; mf < 2; ++mf)
#pragma unroll
        for (int nf = 0; nf < 2; ++nf) {
            int h = n0 + wn * 32 + nf * 16 + (lane & 15);
            float bb = b1 ? b1[h] : 0.f;
#pragma unroll
            for (int j = 0; j < 4; ++j) {
                int m = m0 + wm * 32 + mf * 16 + (lane >> 4) * 4 + j;
                if (m < M) P[(long)m * 1024 + h] = f2bf(acc[mf][nf][j] + bb);
            }
        }
}

// ---------------- packed H: unit(mb,t): 256 rows x 32 k (16KB) ----------------
__global__ __launch_bounds__(256) void hgen_pk(
        const short* __restrict__ encB, const short* __restrict__ decB,
        short* __restrict__ Hp)
{
    long idx = (long)blockIdx.x * 256 + threadIdx.x;
    int u = (int)(idx >> 10);          // 0 .. 282*32-1
    int gi = (int)(idx & 1023);
    int mb = u >> 5, t = u & 31;
    int r = gi >> 2, g3 = gi & 3;
    int m = mb * 256 + r;
    int k = t * 32 + g3 * 8;
    short8 v = {};
    if (m < M_TOT) {
        int bt = m / U_;
        int uu = m - bt * U_;
        int b = m / (T_ * U_);
        short8 e = *(const short8*)(encB + (long)bt * 1024 + k);
        short8 d = *(const short8*)(decB + (long)(b * U_ + uu) * 1024 + k);
#pragma unroll
        for (int j = 0; j < 8; ++j)
            v[j] = f2bf(fast_tanh(b2f(e[j]) + b2f(d[j])));
    }
    *(short8*)(Hp + (long)u * 8192 + gi * 8) = v;
}

// ---------------- main GEMM: 256x256, BK=32, tri-buffer, 1 barrier/tile -----
// 8 waves (2m x 4n), wave tile 128x64, acc 128 AGPR. LDS 3 x (A 16KB + B 16KB)
// = 96KB. Per K-tile: GATE vmcnt(4) [retires tile t's fills, staged at t-2] ->
// s_barrier -> sched_barrier -> stage(t+2) 4 gl_lds -> 12 plain ds_reads ->
// 2 x 16-MFMA clusters. NO hand lgkm waits (compiler derives counted waits
// from real register deps), NO closing barrier (next tile's rendezvous gives
// WAR safety: all reads are consumed by MFMAs whose waitcnts retire them
// before barrier arrival). Bank swizzle g ^= (row>>1)&3 -> exact 2-way (free).
__global__ __launch_bounds__(512, 2) void gemm_t3(
        const short* __restrict__ Hp,   // units (mb,t) 256x32
        const short* __restrict__ W2p,  // units (nb,t) 256x32
        const float* __restrict__ b2,
        float* __restrict__ out)        // [M_TOT][V_] fp32
{
    __shared__ __align__(16) char lds[3 * 32768];

    const int tid = threadIdx.x;
    const int lane = tid & 63;
    const int w = tid >> 6;
    const int wm = w >> 2, wn = w & 3;
    const int l15 = lane & 15, ksel = lane >> 4;

    // bijective XCD swizzle (nwg = 1128 = 8*141, r=0)
    const int nwg = gridDim.x;
    int bid = blockIdx.x;
    int q = nwg >> 3, r = nwg & 7;
    int xcd = bid & 7, lq = bid >> 3;
    int wg = (xcd < r ? xcd * (q + 1) : r * (q + 1) + (xcd - r) * q) + lq;
    const int mb = wg >> 2, nb = wg & 3;

    // staging: thread -> granules gi=tid and gi=512+tid of each 16KB unit.
    // LDS linear granule (row,g') holds source granule g = g' ^ ((row>>1)&3);
    // row(gi+512) = row+128 keeps the same XOR, so src2 = src + 4096 shorts.
    const int srow = tid >> 2;
    const int sg = (tid & 3) ^ ((srow >> 1) & 3);
    const short* a0 = Hp  + (long)mb * 32 * 8192 + srow * 32 + sg * 8;
    const short* b0 = W2p + (long)nb * 32 * 8192 + srow * 32 + sg * 8;
    char* const dW = (char*)lds + (w << 10);   // wave-uniform dest base

#define ST(t_, b_) do {                                                      \
    gl_lds16(a0 + (long)(t_) * 8192,        dW + (b_) * 32768);              \
    gl_lds16(a0 + (long)(t_) * 8192 + 4096, dW + (b_) * 32768 + 8192);       \
    gl_lds16(b0 + (long)(t_) * 8192,        dW + (b_) * 32768 + 16384);      \
    gl_lds16(b0 + (long)(t_) * 8192 + 4096, dW + (b_) * 32768 + 24576);      \
} while (0)

    short8 af[4], bf[4];
    f32x4 acc[8][4] = {};

#define RD_B(b_) do {                                                        \
    _Pragma("unroll")                                                        \
    for (int nf = 0; nf < 4; ++nf) {                                         \
        const int rw_ = wn * 64 + nf * 16 + l15;                             \
        bf[nf] = *(const short8*)((const char*)lds + (b_) * 32768 + 16384    \
            + rw_ * 64 + ((ksel ^ ((rw_ >> 1) & 3)) << 4));                  \
    } } while (0)

#define RD_A(b_, qm_) do {                                                   \
    _Pragma("unroll")                                                        \
    for (int mf = 0; mf < 4; ++mf) {                                         \
        const int rw_ = wm * 128 + (qm_) * 64 + mf * 16 + l15;               \
        af[mf] = *(const short8*)((const char*)lds + (b_) * 32768            \
            + rw_ * 64 + ((ksel ^ ((rw_ >> 1) & 3)) << 4));                  \
    } } while (0)

#define MM(qm_) do {                                                         \
    __builtin_amdgcn_s_setprio(1);                                           \
    _Pragma("unroll")                                                        \
    for (int nf = 0; nf < 4; ++nf)                                           \
        _Pragma("unroll")                                                    \
        for (int mf = 0; mf < 4; ++mf)                                       \
            acc[(qm_) * 4 + mf][nf] = __builtin_amdgcn_mfma_f32_16x16x32_bf16( \
                af[mf], bf[nf], acc[(qm_) * 4 + mf][nf], 0, 0, 0);           \
    __builtin_amdgcn_s_setprio(0);                                           \
} while (0)

#define TILE(t_, b_, b2_, DO_, GN_) do {                                     \
    asm volatile("s_waitcnt vmcnt(" GN_ ")" ::: "memory");                   \
    __builtin_amdgcn_s_barrier();                                            \
    __builtin_amdgcn_sched_barrier(0);                                       \
    if (DO_) ST((t_) + 2, b2_);                                              \
    RD_B(b_);                                                                \
    RD_A(b_, 0);                                                             \
    MM(0);                                                                   \
    RD_A(b_, 1);                                                             \
    MM(1);                                                                   \
} while (0)

    // prologue: stage tiles 0 and 1 (8 gl_lds/thread outstanding)
    ST(0, 0);
    ST(1, 1);

#pragma unroll 1
    for (int t = 0; t < 30; t += 3) {
        TILE(t,     0, 2, true, "4");
        TILE(t + 1, 1, 0, true, "4");
        TILE(t + 2, 2, 1, true, "4");
    }
    TILE(30, 0, 2, false, "4");
    TILE(31, 1, 0, false, "0");

    // epilogue: + b2, store fp32
#pragma unroll
    for (int nf = 0; nf < 4; ++nf) {
        int n = nb * 256 + wn * 64 + nf * 16 + l15;
        if (n < V_) {
            float bv = b2[n];
#pragma unroll
            for (int qm = 0; qm < 2; ++qm)
#pragma unroll
                for (int mf = 0; mf < 4; ++mf)
#pragma unroll
                    for (int j = 0; j < 4; ++j) {
                        int m = mb * 256 + wm * 128 + qm * 64 + mf * 16 + ksel * 4 + j;
                        if (m < M_TOT)
                            out[(long)m * V_ + n] = acc[qm * 4 + mf][nf][j] + bv;
                    }
        }
    }
#undef ST
#undef RD_B
#undef RD_A
#undef MM
#undef TILE
}

// ---------------- launch ----------------
extern "C" void kernel_launch(void* const* d_in, const int* in_sizes, int n_in,
                              void* d_out, int out_size, void* d_ws, size_t ws_size,
                              hipStream_t stream) {
    const float* enc = (const float*)d_in[0];
    const float* dec = (const float*)d_in[1];
    const float* W1  = (const float*)d_in[2];
    const float* b1  = (const float*)d_in[3];
    const float* W2  = (const float*)d_in[4];
    const float* b2  = (const float*)d_in[5];
    float* out = (float*)d_out;

    char* ws = (char*)d_ws;
    size_t off = 0;
    short* W1t  = (short*)(ws + off); off += (size_t)1024 * WK * 2;      // 2.06 MB
    short* W2p  = (short*)(ws + off); off += (size_t)4 * 32 * 8192 * 2;  // 2.00 MB
    short* encB = (short*)(ws + off); off += (size_t)1216 * 1024 * 2;    // 2.43 MB
    short* decB = (short*)(ws + off); off += (size_t)256 * 1024 * 2;     // 0.50 MB
    short* Hp   = (short*)(ws + off);                                    // 144.4 MB

    transpose_cvt<<<dim3(16, 16), 256, 0, stream>>>(W1, W1t, 1024, 1024, WK);
    transpose_pack_w2<<<dim3(16, 16), 256, 0, stream>>>(W2, W2p);
    proj_gemm<<<dim3(19, 16), 256, 0, stream>>>(enc, 1200, 0,   W1t, nullptr, encB);
    proj_gemm<<<dim3(4, 16),  256, 0, stream>>>(dec, 240,  512, W1t, b1,      decB);

    hgen_pk<<<MBCNT * 32 * 1024 / 256, 256, 0, stream>>>(encB, decB, Hp);
    gemm_t3<<<MBCNT * 4, 512, 0, stream>>>(Hp, W2p, b2, out);
}

// Round 13
// 330.950 us; speedup vs baseline: 1.1909x; 1.0620x over previous
//
#include <hip/hip_runtime.h>
#include <hip/hip_bf16.h>
#include <stdint.h>

#define B_  4
#define T_  300
#define U_  60
#define V_  1000
#define M_TOT (B_*T_*U_)   // 72000
#define MB_CNT 563         // ceil(72000/128)
#define WK  1056           // padded W1t row stride (shorts)

typedef __attribute__((ext_vector_type(8))) short short8;
typedef __attribute__((ext_vector_type(4))) float f32x4;
typedef __attribute__((ext_vector_type(4))) int int4v;

__device__ __forceinline__ short f2bf(float f) {
    union { float f; uint32_t u; } c; c.f = f;
    uint32_t u = c.u;
    uint32_t r = (u + 0x7FFFu + ((u >> 16) & 1u)) >> 16;
    return (short)r;
}

__device__ __forceinline__ float b2f(short s) {
    union { float f; uint32_t u; } c;
    c.u = ((uint32_t)(uint16_t)s) << 16;
    return c.f;
}

__device__ __forceinline__ float fast_tanh(float x) {
    float e = __expf(2.0f * x);
    float r = __builtin_amdgcn_rcpf(e + 1.0f);
    return 1.0f - 2.0f * r;
}

__device__ __forceinline__ void gl_lds16(const void* g, void* l) {
    __builtin_amdgcn_global_load_lds(
        (const __attribute__((address_space(1))) void*)g,
        (__attribute__((address_space(3))) void*)l, 16, 0, 0);
}

// ---------------- merged weight prep ----------------
// z=0: W1 fp32 [1024][1024] -> bf16 W1t [1024 h][WK k]
// z=1: W2 fp32 [1024 k][1000 v] -> packed units W2p[(nb*32+kt)*8192 + pr*32 + ks]
__global__ void prep_weights(const float* __restrict__ W1, const float* __restrict__ W2,
                             short* __restrict__ W1t, short* __restrict__ W2p) {
    __shared__ float tile[64][65];
    const int tx = threadIdx.x & 63, ty = threadIdx.x >> 6;
    const int r0 = blockIdx.y * 64, c0 = blockIdx.x * 64;
    if (blockIdx.z == 0) {
#pragma unroll
        for (int i = 0; i < 16; ++i) {
            int r = r0 + i * 4 + ty, c = c0 + tx;
            tile[i * 4 + ty][tx] = W1[(long)r * 1024 + c];
        }
        __syncthreads();
#pragma unroll
        for (int i = 0; i < 16; ++i) {
            int oc = c0 + i * 4 + ty;
            int orr = r0 + tx;
            W1t[(long)oc * WK + orr] = f2bf(tile[tx][i * 4 + ty]);
        }
    } else {
#pragma unroll
        for (int i = 0; i < 16; ++i) {
            int r = r0 + i * 4 + ty, c = c0 + tx;   // r=k, c=v
            float v = 0.f;
            if (c < V_) v = W2[(long)r * V_ + c];
            tile[i * 4 + ty][tx] = v;
        }
        __syncthreads();
#pragma unroll
        for (int i = 0; i < 16; ++i) {
            int oc = c0 + i * 4 + ty;       // v 0..1023
            int orr = r0 + tx;              // k 0..1023
            int nb = oc >> 8, prow = oc & 255, kt = orr >> 5, ks = orr & 31;
            W2p[(long)(nb * 32 + kt) * 8192 + prow * 32 + ks] = f2bf(tile[tx][i * 4 + ty]);
        }
    }
}

// ---------------- merged projections (bf16 out) ----------------
// bx<19: encB[1200][1024] from enc (koff=0, no bias)
// bx>=19: decB[240][1024] from dec (koff=512, +b1)
__global__ __launch_bounds__(256, 2) void proj_both(
        const float* __restrict__ enc, const float* __restrict__ dec,
        const short* __restrict__ Wt, const float* __restrict__ b1,
        short* __restrict__ encB, short* __restrict__ decB)
{
    __shared__ short As[64 * 64];
    const int tid = threadIdx.x;
    const int lane = tid & 63;
    const int w = tid >> 6;
    const int wm = w >> 1, wn = w & 1;

    const int bx = blockIdx.x;
    const bool isenc = bx < 19;
    const float* X  = isenc ? enc : dec;
    const int M     = isenc ? 1200 : 240;
    const int k_off = isenc ? 0 : 512;
    short* P        = isenc ? encB : decB;
    const int m0 = (isenc ? bx : bx - 19) * 64;
    const int n0 = blockIdx.y * 64;

    f32x4 acc[2][2] = {};
    for (int k0 = 0; k0 < 512; k0 += 64) {
#pragma unroll
        for (int c = 0; c < 2; ++c) {
            int lin = tid + 256 * c;
            int row = lin >> 3, k8 = lin & 7;
            int m = m0 + row;
            short vals[8];
            if (m < M) {
                const float* xp = X + (long)m * 512 + k0 + k8 * 8;
#pragma unroll
                for (int j = 0; j < 8; ++j) vals[j] = f2bf(xp[j]);
            } else {
#pragma unroll
                for (int j = 0; j < 8; ++j) vals[j] = 0;
            }
            int byte = row * 128 + k8 * 16;
            byte ^= (row & 7) << 4;
            *(int4v*)((char*)As + byte) = *(const int4v*)vals;
        }
        __syncthreads();
#pragma unroll
        for (int ks = 0; ks < 2; ++ks) {
            short8 af[2];
#pragma unroll
            for (int mf = 0; mf < 2; ++mf) {
                int row = wm * 32 + mf * 16 + (lane & 15);
                int byte = row * 128 + ks * 64 + (lane >> 4) * 16;
                byte ^= (row & 7) << 4;
                af[mf] = *(const short8*)((char*)As + byte);
            }
#pragma unroll
            for (int nf = 0; nf < 2; ++nf) {
                int h = n0 + wn * 32 + nf * 16 + (lane & 15);
                const short* bp = Wt + (long)h * WK + k_off + k0 + ks * 32 + (lane >> 4) * 8;
                short8 bfv = *(const short8*)bp;
#pragma unroll
                for (int mf = 0; mf < 2; ++mf)
                    acc[mf][nf] = __builtin_amdgcn_mfma_f32_16x16x32_bf16(af[mf], bfv, acc[mf][nf], 0, 0, 0);
            }
        }
        __syncthreads();
    }
#pragma unroll
    for (int mf = 0; mf < 2; ++mf)
#pragma unroll
        for (int nf = 0; nf < 2; ++nf) {
            int h = n0 + wn * 32 + nf * 16 + (lane & 15);
            float bb = isenc ? 0.f : b1[h];
#pragma unroll
            for (int j = 0; j < 4; ++j) {
                int m = m0 + wm * 32 + mf * 16 + (lane >> 4) * 4 + j;
                if (m < M) P[(long)m * 1024 + h] = f2bf(acc[mf][nf][j] + bb);
            }
        }
}

// ---------------- packed H (R8 unit layout, bf16 inputs) ----------------
// unit u = mb*32+kt: 128 rows x 32 shorts (8KB); thread -> one 16B granule.
__global__ __launch_bounds__(256) void hgen_pk(
        const short* __restrict__ encB, const short* __restrict__ decB,
        short* __restrict__ Hp)
{
    long idx = (long)blockIdx.x * 256 + threadIdx.x;
    int u = (int)(idx >> 9);           // 0 .. 563*32-1
    int gi = (int)(idx & 511);
    int mb = u >> 5, kt = u & 31;
    int r = gi >> 2, g = gi & 3;
    int m = mb * 128 + r;
    int k = kt * 32 + g * 8;
    short8 v = {};
    if (m < M_TOT) {
        int bt = m / U_;
        int uu = m - bt * U_;
        int b = m / (T_ * U_);
        short8 e = *(const short8*)(encB + (long)bt * 1024 + k);
        short8 d = *(const short8*)(decB + (long)(b * U_ + uu) * 1024 + k);
#pragma unroll
        for (int j = 0; j < 8; ++j)
            v[j] = f2bf(fast_tanh(b2f(e[j]) + b2f(d[j])));
    }
    *(short8*)(Hp + (long)u * 4096 + gi * 8) = v;
}

// ---------------- main GEMM (R8 gemm_pk, verbatim — best measured) ----------
// BM=128, BN=256, wave tile 64x64 (8 waves 2m x 4n), BK=32, 32 K-tiles.
// 3-slot LDS ring (24KB/slot, 72KB) -> 2 blocks/CU. Contiguous packed units,
// granule-permuted source. 3 gl_lds/thread/tile, prefetch distance 2,
// counted gate vmcnt(3) once per tile.
__global__ __launch_bounds__(512, 4) void gemm_pk(
        const short* __restrict__ Hp,   // [563*32 units][4096 shorts]
        const short* __restrict__ W2p,  // [4*32 units][8192 shorts]
        const float* __restrict__ b2,
        float* __restrict__ out)        // [M_TOT][V_]
{
    __shared__ __align__(16) char lds[3 * 24576];

    const int tid = threadIdx.x;
    const int lane = tid & 63;
    const int w = tid >> 6;            // 0..7
    const int wm = w >> 2, wn = w & 3; // 2m x 4n
    const int l15 = lane & 15, ksel = lane >> 4;

    const int nwg = gridDim.x;
    int bid = blockIdx.x;
    int q = nwg >> 3, r = nwg & 7;
    int xcd = bid & 7, lq = bid >> 3;
    int wg = (xcd < r ? xcd * (q + 1) : r * (q + 1) + (xcd - r) * q) + lq;
    const int mb = wg >> 2;            // 0..562
    const int nb = wg & 3;
    const int m0 = mb * 128, n0 = nb * 256;

    const int sr = tid >> 2;
    const int sg = (tid & 3) ^ ((sr >> 1) & 3);
    const short* aU = Hp + (long)mb * 32 * 4096 + sr * 32 + sg * 8;
    const short* bU = W2p + (long)nb * 32 * 8192 + sr * 32 + sg * 8;
    char* const ldsw = (char*)lds + (w << 10);

#define STAGE_A(t_, sl_) gl_lds16(aU + (long)(t_) * 4096, ldsw + (sl_) * 24576)
#define STAGE_B(t_, sl_) do {                                               \
    char* db_ = ldsw + (sl_) * 24576 + 8192;                                \
    gl_lds16(bU + (long)(t_) * 8192, db_);                                  \
    gl_lds16(bU + (long)(t_) * 8192 + 4096, db_ + 8192);                    \
} while (0)

    f32x4 acc[4][4] = {};
    short8 af[4], bf[4];

#define PH_A(sl_, DOSTAGE, t2_, ss_) do {                                   \
    const char* Ab_ = (const char*)lds + (sl_) * 24576;                     \
    const char* Bb_ = Ab_ + 8192;                                           \
    _Pragma("unroll")                                                       \
    for (int nf = 0; nf < 2; ++nf) {                                        \
        int rw = wn * 64 + nf * 16 + l15;                                   \
        bf[nf] = *(const short8*)(Bb_ + rw * 64 + ((ksel ^ ((rw >> 1) & 3)) << 4)); \
    }                                                                       \
    _Pragma("unroll")                                                       \
    for (int mf = 0; mf < 4; ++mf) {                                        \
        int rw = wm * 64 + mf * 16 + l15;                                   \
        af[mf] = *(const short8*)(Ab_ + rw * 64 + ((ksel ^ ((rw >> 1) & 3)) << 4)); \
    }                                                                       \
    if (DOSTAGE) STAGE_A(t2_, ss_);                                         \
    __builtin_amdgcn_s_barrier();                                           \
    asm volatile("s_waitcnt lgkmcnt(0)" ::: "memory");                      \
    __builtin_amdgcn_s_setprio(1);                                          \
    _Pragma("unroll")                                                       \
    for (int nf = 0; nf < 2; ++nf)                                          \
        _Pragma("unroll")                                                   \
        for (int mf = 0; mf < 4; ++mf)                                      \
            acc[mf][nf] = __builtin_amdgcn_mfma_f32_16x16x32_bf16(          \
                af[mf], bf[nf], acc[mf][nf], 0, 0, 0);                      \
    __builtin_amdgcn_s_setprio(0);                                          \
    __builtin_amdgcn_s_barrier();                                           \
} while (0)

#define PH_B(sl_, DOSTAGE, t2_, ss_, GATE) do {                             \
    const char* Ab_ = (const char*)lds + (sl_) * 24576;                     \
    const char* Bb_ = Ab_ + 8192;                                           \
    _Pragma("unroll")                                                       \
    for (int nf = 2; nf < 4; ++nf) {                                        \
        int rw = wn * 64 + nf * 16 + l15;                                   \
        bf[nf] = *(const short8*)(Bb_ + rw * 64 + ((ksel ^ ((rw >> 1) & 3)) << 4)); \
    }                                                                       \
    if (DOSTAGE) STAGE_B(t2_, ss_);                                         \
    GATE                                                                    \
    __builtin_amdgcn_s_barrier();                                           \
    asm volatile("s_waitcnt lgkmcnt(0)" ::: "memory");                      \
    __builtin_amdgcn_s_setprio(1);                                          \
    _Pragma("unroll")                                                       \
    for (int nf = 2; nf < 4; ++nf)                                          \
        _Pragma("unroll")                                                   \
        for (int mf = 0; mf < 4; ++mf)                                      \
            acc[mf][nf] = __builtin_amdgcn_mfma_f32_16x16x32_bf16(          \
                af[mf], bf[nf], acc[mf][nf], 0, 0, 0);                      \
    __builtin_amdgcn_s_setprio(0);                                          \
    __builtin_amdgcn_s_barrier();                                           \
} while (0)

#define GATE3 asm volatile("s_waitcnt vmcnt(3)" ::: "memory");
#define GATE0 asm volatile("s_waitcnt vmcnt(0)" ::: "memory");
#define NOGATE

    STAGE_A(0, 0); STAGE_B(0, 0);
    STAGE_A(1, 1); STAGE_B(1, 1);
    asm volatile("s_waitcnt vmcnt(3)" ::: "memory");
    __builtin_amdgcn_s_barrier();

    int s = 0, ss = 2;
#pragma unroll 1
    for (int t = 0; t < 30; ++t) {
        PH_A(s, true, t + 2, ss);
        PH_B(s, true, t + 2, ss, GATE3);
        s = (s == 2) ? 0 : s + 1;
        ss = (ss == 2) ? 0 : ss + 1;
    }
    PH_A(s, false, 0, 0); PH_B(s, false, 0, 0, GATE0);
    s = (s == 2) ? 0 : s + 1;
    PH_A(s, false, 0, 0); PH_B(s, false, 0, 0, NOGATE);

#pragma unroll
    for (int nf = 0; nf < 4; ++nf) {
        int n = n0 + wn * 64 + nf * 16 + l15;
        if (n < V_) {
            float bv = b2[n];
#pragma unroll
            for (int mf = 0; mf < 4; ++mf)
#pragma unroll
                for (int j = 0; j < 4; ++j) {
                    int m = m0 + wm * 64 + mf * 16 + ksel * 4 + j;
                    if (m < M_TOT)
                        out[(long)m * V_ + n] = acc[mf][nf][j] + bv;
                }
        }
    }
#undef PH_A
#undef PH_B
#undef STAGE_A
#undef STAGE_B
#undef GATE3
#undef GATE0
#undef NOGATE
}

// ---------------- launch ----------------
extern "C" void kernel_launch(void* const* d_in, const int* in_sizes, int n_in,
                              void* d_out, int out_size, void* d_ws, size_t ws_size,
                              hipStream_t stream) {
    const float* enc = (const float*)d_in[0];
    const float* dec = (const float*)d_in[1];
    const float* W1  = (const float*)d_in[2];
    const float* b1  = (const float*)d_in[3];
    const float* W2  = (const float*)d_in[4];
    const float* b2  = (const float*)d_in[5];
    float* out = (float*)d_out;

    char* ws = (char*)d_ws;
    size_t off = 0;
    short* W1t  = (short*)(ws + off); off += (size_t)1024 * WK * 2;          // 2.06 MB
    short* W2p  = (short*)(ws + off); off += (size_t)4 * 32 * 8192 * 2;      // 2.00 MB
    short* encB = (short*)(ws + off); off += (size_t)1216 * 1024 * 2;        // 2.49 MB
    short* decB = (short*)(ws + off); off += (size_t)256 * 1024 * 2;         // 0.52 MB
    short* Hp   = (short*)(ws + off);                                        // 147.6 MB

    // 4 launches: weights -> projections -> H -> GEMM
    prep_weights<<<dim3(16, 16, 2), 256, 0, stream>>>(W1, W2, W1t, W2p);
    proj_both<<<dim3(23, 16), 256, 0, stream>>>(enc, dec, W1t, b1, encB, decB);
    hgen_pk<<<MB_CNT * 32 * 512 / 256, 256, 0, stream>>>(encB, decB, Hp);
    gemm_pk<<<MB_CNT * 4, 512, 0, stream>>>(Hp, W2p, b2, out);
}

// Round 14
// 318.975 us; speedup vs baseline: 1.2356x; 1.0375x over previous
//
#include <hip/hip_runtime.h>
#include <hip/hip_bf16.h>
#include <stdint.h>

#define B_  4
#define T_  300
#define U_  60
#define V_  1000
#define M_TOT (B_*T_*U_)   // 72000
#define MB_CNT 563         // ceil(72000/128)
#define WK  1056           // padded W1t row stride (shorts)

typedef __attribute__((ext_vector_type(8))) short short8;
typedef __attribute__((ext_vector_type(4))) float f32x4;
typedef __attribute__((ext_vector_type(4))) int int4v;

__device__ __forceinline__ short f2bf(float f) {
    union { float f; uint32_t u; } c; c.f = f;
    uint32_t u = c.u;
    uint32_t r = (u + 0x7FFFu + ((u >> 16) & 1u)) >> 16;
    return (short)r;
}

__device__ __forceinline__ float b2f(short s) {
    union { float f; uint32_t u; } c;
    c.u = ((uint32_t)(uint16_t)s) << 16;
    return c.f;
}

__device__ __forceinline__ float fast_tanh(float x) {
    float e = __expf(2.0f * x);
    float r = __builtin_amdgcn_rcpf(e + 1.0f);
    return 1.0f - 2.0f * r;
}

__device__ __forceinline__ void gl_lds16(const void* g, void* l) {
    __builtin_amdgcn_global_load_lds(
        (const __attribute__((address_space(1))) void*)g,
        (__attribute__((address_space(3))) void*)l, 16, 0, 0);
}

// ---------------- merged weight prep ----------------
__global__ void prep_weights(const float* __restrict__ W1, const float* __restrict__ W2,
                             short* __restrict__ W1t, short* __restrict__ W2p) {
    __shared__ float tile[64][65];
    const int tx = threadIdx.x & 63, ty = threadIdx.x >> 6;
    const int r0 = blockIdx.y * 64, c0 = blockIdx.x * 64;
    if (blockIdx.z == 0) {
#pragma unroll
        for (int i = 0; i < 16; ++i) {
            int r = r0 + i * 4 + ty, c = c0 + tx;
            tile[i * 4 + ty][tx] = W1[(long)r * 1024 + c];
        }
        __syncthreads();
#pragma unroll
        for (int i = 0; i < 16; ++i) {
            int oc = c0 + i * 4 + ty;
            int orr = r0 + tx;
            W1t[(long)oc * WK + orr] = f2bf(tile[tx][i * 4 + ty]);
        }
    } else {
#pragma unroll
        for (int i = 0; i < 16; ++i) {
            int r = r0 + i * 4 + ty, c = c0 + tx;   // r=k, c=v
            float v = 0.f;
            if (c < V_) v = W2[(long)r * V_ + c];
            tile[i * 4 + ty][tx] = v;
        }
        __syncthreads();
#pragma unroll
        for (int i = 0; i < 16; ++i) {
            int oc = c0 + i * 4 + ty;       // v 0..1023
            int orr = r0 + tx;              // k 0..1023
            int nb = oc >> 8, prow = oc & 255, kt = orr >> 5, ks = orr & 31;
            W2p[(long)(nb * 32 + kt) * 8192 + prow * 32 + ks] = f2bf(tile[tx][i * 4 + ty]);
        }
    }
}

// ---------------- merged projections (bf16 out) ----------------
__global__ __launch_bounds__(256, 2) void proj_both(
        const float* __restrict__ enc, const float* __restrict__ dec,
        const short* __restrict__ Wt, const float* __restrict__ b1,
        short* __restrict__ encB, short* __restrict__ decB)
{
    __shared__ short As[64 * 64];
    const int tid = threadIdx.x;
    const int lane = tid & 63;
    const int w = tid >> 6;
    const int wm = w >> 1, wn = w & 1;

    const int bx = blockIdx.x;
    const bool isenc = bx < 19;
    const float* X  = isenc ? enc : dec;
    const int M     = isenc ? 1200 : 240;
    const int k_off = isenc ? 0 : 512;
    short* P        = isenc ? encB : decB;
    const int m0 = (isenc ? bx : bx - 19) * 64;
    const int n0 = blockIdx.y * 64;

    f32x4 acc[2][2] = {};
    for (int k0 = 0; k0 < 512; k0 += 64) {
#pragma unroll
        for (int c = 0; c < 2; ++c) {
            int lin = tid + 256 * c;
            int row = lin >> 3, k8 = lin & 7;
            int m = m0 + row;
            short vals[8];
            if (m < M) {
                const float* xp = X + (long)m * 512 + k0 + k8 * 8;
#pragma unroll
                for (int j = 0; j < 8; ++j) vals[j] = f2bf(xp[j]);
            } else {
#pragma unroll
                for (int j = 0; j < 8; ++j) vals[j] = 0;
            }
            int byte = row * 128 + k8 * 16;
            byte ^= (row & 7) << 4;
            *(int4v*)((char*)As + byte) = *(const int4v*)vals;
        }
        __syncthreads();
#pragma unroll
        for (int ks = 0; ks < 2; ++ks) {
            short8 af[2];
#pragma unroll
            for (int mf = 0; mf < 2; ++mf) {
                int row = wm * 32 + mf * 16 + (lane & 15);
                int byte = row * 128 + ks * 64 + (lane >> 4) * 16;
                byte ^= (row & 7) << 4;
                af[mf] = *(const short8*)((char*)As + byte);
            }
#pragma unroll
            for (int nf = 0; nf < 2; ++nf) {
                int h = n0 + wn * 32 + nf * 16 + (lane & 15);
                const short* bp = Wt + (long)h * WK + k_off + k0 + ks * 32 + (lane >> 4) * 8;
                short8 bfv = *(const short8*)bp;
#pragma unroll
                for (int mf = 0; mf < 2; ++mf)
                    acc[mf][nf] = __builtin_amdgcn_mfma_f32_16x16x32_bf16(af[mf], bfv, acc[mf][nf], 0, 0, 0);
            }
        }
        __syncthreads();
    }
#pragma unroll
    for (int mf = 0; mf < 2; ++mf)
#pragma unroll
        for (int nf = 0; nf < 2; ++nf) {
            int h = n0 + wn * 32 + nf * 16 + (lane & 15);
            float bb = isenc ? 0.f : b1[h];
#pragma unroll
            for (int j = 0; j < 4; ++j) {
                int m = m0 + wm * 32 + mf * 16 + (lane >> 4) * 4 + j;
                if (m < M) P[(long)m * 1024 + h] = f2bf(acc[mf][nf][j] + bb);
            }
        }
}

// ---------------- packed H (bf16 inputs) ----------------
__global__ __launch_bounds__(256) void hgen_pk(
        const short* __restrict__ encB, const short* __restrict__ decB,
        short* __restrict__ Hp)
{
    long idx = (long)blockIdx.x * 256 + threadIdx.x;
    int u = (int)(idx >> 9);           // 0 .. 563*32-1
    int gi = (int)(idx & 511);
    int mb = u >> 5, kt = u & 31;
    int r = gi >> 2, g = gi & 3;
    int m = mb * 128 + r;
    int k = kt * 32 + g * 8;
    short8 v = {};
    if (m < M_TOT) {
        int bt = m / U_;
        int uu = m - bt * U_;
        int b = m / (T_ * U_);
        short8 e = *(const short8*)(encB + (long)bt * 1024 + k);
        short8 d = *(const short8*)(decB + (long)(b * U_ + uu) * 1024 + k);
#pragma unroll
        for (int j = 0; j < 8; ++j)
            v[j] = f2bf(fast_tanh(b2f(e[j]) + b2f(d[j])));
    }
    *(short8*)(Hp + (long)u * 4096 + gi * 8) = v;
}

// ---------------- main GEMM (R8/R13 gemm_pk + block de-phasing) ----------
// BM=128, BN=256, wave tile 64x64 (8 waves 2m x 4n), BK=32, 32 K-tiles.
// 3-slot LDS ring (24KB/slot, 72KB) -> 2 blocks/CU.
// NEW: a pseudo-random half of blocks sleep ~2240 cyc (~half a tile-slot)
// once at entry, de-phasing co-resident blocks so their LDS/MFMA bursts
// interleave instead of colliding (R8==R9 perf showed in-phase co-residency
// buys nothing). Cost if wrong: ~0.35%.
__global__ __launch_bounds__(512, 4) void gemm_pk(
        const short* __restrict__ Hp,   // [563*32 units][4096 shorts]
        const short* __restrict__ W2p,  // [4*32 units][8192 shorts]
        const float* __restrict__ b2,
        float* __restrict__ out)        // [M_TOT][V_]
{
    __shared__ __align__(16) char lds[3 * 24576];

    const int tid = threadIdx.x;
    const int lane = tid & 63;
    const int w = tid >> 6;            // 0..7
    const int wm = w >> 2, wn = w & 3; // 2m x 4n
    const int l15 = lane & 15, ksel = lane >> 4;

    const int nwg = gridDim.x;
    int bid = blockIdx.x;
    int q = nwg >> 3, r = nwg & 7;
    int xcd = bid & 7, lq = bid >> 3;
    int wg = (xcd < r ? xcd * (q + 1) : r * (q + 1) + (xcd - r) * q) + lq;
    const int mb = wg >> 2;            // 0..562
    const int nb = wg & 3;
    const int m0 = mb * 128, n0 = nb * 256;

    // de-phase: half the blocks (hash-selected, pairing-agnostic) start
    // ~half a tile-slot late; equal loop periods keep the offset forever.
    if ((uint32_t)(wg * 2654435761u) & 0x80000000u) {
        __builtin_amdgcn_s_sleep(7);
        __builtin_amdgcn_s_sleep(7);
        __builtin_amdgcn_s_sleep(7);
        __builtin_amdgcn_s_sleep(7);
        __builtin_amdgcn_s_sleep(7);
    }

    const int sr = tid >> 2;
    const int sg = (tid & 3) ^ ((sr >> 1) & 3);
    const short* aU = Hp + (long)mb * 32 * 4096 + sr * 32 + sg * 8;
    const short* bU = W2p + (long)nb * 32 * 8192 + sr * 32 + sg * 8;
    char* const ldsw = (char*)lds + (w << 10);

#define STAGE_A(t_, sl_) gl_lds16(aU + (long)(t_) * 4096, ldsw + (sl_) * 24576)
#define STAGE_B(t_, sl_) do {                                               \
    char* db_ = ldsw + (sl_) * 24576 + 8192;                                \
    gl_lds16(bU + (long)(t_) * 8192, db_);                                  \
    gl_lds16(bU + (long)(t_) * 8192 + 4096, db_ + 8192);                    \
} while (0)

    f32x4 acc[4][4] = {};
    short8 af[4], bf[4];

#define PH_A(sl_, DOSTAGE, t2_, ss_) do {                                   \
    const char* Ab_ = (const char*)lds + (sl_) * 24576;                     \
    const char* Bb_ = Ab_ + 8192;                                           \
    _Pragma("unroll")                                                       \
    for (int nf = 0; nf < 2; ++nf) {                                        \
        int rw = wn * 64 + nf * 16 + l15;                                   \
        bf[nf] = *(const short8*)(Bb_ + rw * 64 + ((ksel ^ ((rw >> 1) & 3)) << 4)); \
    }                                                                       \
    _Pragma("unroll")                                                       \
    for (int mf = 0; mf < 4; ++mf) {                                        \
        int rw = wm * 64 + mf * 16 + l15;                                   \
        af[mf] = *(const short8*)(Ab_ + rw * 64 + ((ksel ^ ((rw >> 1) & 3)) << 4)); \
    }                                                                       \
    if (DOSTAGE) STAGE_A(t2_, ss_);                                         \
    __builtin_amdgcn_s_barrier();                                           \
    asm volatile("s_waitcnt lgkmcnt(0)" ::: "memory");                      \
    __builtin_amdgcn_s_setprio(1);                                          \
    _Pragma("unroll")                                                       \
    for (int nf = 0; nf < 2; ++nf)                                          \
        _Pragma("unroll")                                                   \
        for (int mf = 0; mf < 4; ++mf)                                      \
            acc[mf][nf] = __builtin_amdgcn_mfma_f32_16x16x32_bf16(          \
                af[mf], bf[nf], acc[mf][nf], 0, 0, 0);                      \
    __builtin_amdgcn_s_setprio(0);                                          \
    __builtin_amdgcn_s_barrier();                                           \
} while (0)

#define PH_B(sl_, DOSTAGE, t2_, ss_, GATE) do {                             \
    const char* Ab_ = (const char*)lds + (sl_) * 24576;                     \
    const char* Bb_ = Ab_ + 8192;                                           \
    _Pragma("unroll")                                                       \
    for (int nf = 2; nf < 4; ++nf) {                                        \
        int rw = wn * 64 + nf * 16 + l15;                                   \
        bf[nf] = *(const short8*)(Bb_ + rw * 64 + ((ksel ^ ((rw >> 1) & 3)) << 4)); \
    }                                                                       \
    if (DOSTAGE) STAGE_B(t2_, ss_);                                         \
    GATE                                                                    \
    __builtin_amdgcn_s_barrier();                                           \
    asm volatile("s_waitcnt lgkmcnt(0)" ::: "memory");                      \
    __builtin_amdgcn_s_setprio(1);                                          \
    _Pragma("unroll")                                                       \
    for (int nf = 2; nf < 4; ++nf)                                          \
        _Pragma("unroll")                                                   \
        for (int mf = 0; mf < 4; ++mf)                                      \
            acc[mf][nf] = __builtin_amdgcn_mfma_f32_16x16x32_bf16(          \
                af[mf], bf[nf], acc[mf][nf], 0, 0, 0);                      \
    __builtin_amdgcn_s_setprio(0);                                          \
    __builtin_amdgcn_s_barrier();                                           \
} while (0)

#define GATE3 asm volatile("s_waitcnt vmcnt(3)" ::: "memory");
#define GATE0 asm volatile("s_waitcnt vmcnt(0)" ::: "memory");
#define NOGATE

    STAGE_A(0, 0); STAGE_B(0, 0);
    STAGE_A(1, 1); STAGE_B(1, 1);
    asm volatile("s_waitcnt vmcnt(3)" ::: "memory");
    __builtin_amdgcn_s_barrier();

    int s = 0, ss = 2;
#pragma unroll 1
    for (int t = 0; t < 30; ++t) {
        PH_A(s, true, t + 2, ss);
        PH_B(s, true, t + 2, ss, GATE3);
        s = (s == 2) ? 0 : s + 1;
        ss = (ss == 2) ? 0 : ss + 1;
    }
    PH_A(s, false, 0, 0); PH_B(s, false, 0, 0, GATE0);
    s = (s == 2) ? 0 : s + 1;
    PH_A(s, false, 0, 0); PH_B(s, false, 0, 0, NOGATE);

#pragma unroll
    for (int nf = 0; nf < 4; ++nf) {
        int n = n0 + wn * 64 + nf * 16 + l15;
        if (n < V_) {
            float bv = b2[n];
#pragma unroll
            for (int mf = 0; mf < 4; ++mf)
#pragma unroll
                for (int j = 0; j < 4; ++j) {
                    int m = m0 + wm * 64 + mf * 16 + ksel * 4 + j;
                    if (m < M_TOT)
                        out[(long)m * V_ + n] = acc[mf][nf][j] + bv;
                }
        }
    }
#undef PH_A
#undef PH_B
#undef STAGE_A
#undef STAGE_B
#undef GATE3
#undef GATE0
#undef NOGATE
}

// ---------------- launch ----------------
extern "C" void kernel_launch(void* const* d_in, const int* in_sizes, int n_in,
                              void* d_out, int out_size, void* d_ws, size_t ws_size,
                              hipStream_t stream) {
    const float* enc = (const float*)d_in[0];
    const float* dec = (const float*)d_in[1];
    const float* W1  = (const float*)d_in[2];
    const float* b1  = (const float*)d_in[3];
    const float* W2  = (const float*)d_in[4];
    const float* b2  = (const float*)d_in[5];
    float* out = (float*)d_out;

    char* ws = (char*)d_ws;
    size_t off = 0;
    short* W1t  = (short*)(ws + off); off += (size_t)1024 * WK * 2;          // 2.06 MB
    short* W2p  = (short*)(ws + off); off += (size_t)4 * 32 * 8192 * 2;      // 2.00 MB
    short* encB = (short*)(ws + off); off += (size_t)1216 * 1024 * 2;        // 2.49 MB
    short* decB = (short*)(ws + off); off += (size_t)256 * 1024 * 2;         // 0.52 MB
    short* Hp   = (short*)(ws + off);                                        // 147.6 MB

    prep_weights<<<dim3(16, 16, 2), 256, 0, stream>>>(W1, W2, W1t, W2p);
    proj_both<<<dim3(23, 16), 256, 0, stream>>>(enc, dec, W1t, b1, encB, decB);
    hgen_pk<<<MB_CNT * 32 * 512 / 256, 256, 0, stream>>>(encB, decB, Hp);
    gemm_pk<<<MB_CNT * 4, 512, 0, stream>>>(Hp, W2p, b2, out);
}

// Round 15
// 308.743 us; speedup vs baseline: 1.2765x; 1.0331x over previous
//
#include <hip/hip_runtime.h>
#include <hip/hip_bf16.h>
#include <stdint.h>

#define B_  4
#define T_  300
#define U_  60
#define V_  1000
#define M_TOT (B_*T_*U_)   // 72000
#define MB_CNT 563         // ceil(72000/128)
#define CH0 282            // chunk 0 mb count
#define CH1 (MB_CNT - CH0) // chunk 1 mb count (281)
#define WK  1056           // padded W1t row stride (shorts)

typedef __attribute__((ext_vector_type(8))) short short8;
typedef __attribute__((ext_vector_type(4))) float f32x4;
typedef __attribute__((ext_vector_type(4))) int int4v;

__device__ __forceinline__ short f2bf(float f) {
    union { float f; uint32_t u; } c; c.f = f;
    uint32_t u = c.u;
    uint32_t r = (u + 0x7FFFu + ((u >> 16) & 1u)) >> 16;
    return (short)r;
}

__device__ __forceinline__ float b2f(short s) {
    union { float f; uint32_t u; } c;
    c.u = ((uint32_t)(uint16_t)s) << 16;
    return c.f;
}

__device__ __forceinline__ float fast_tanh(float x) {
    float e = __expf(2.0f * x);
    float r = __builtin_amdgcn_rcpf(e + 1.0f);
    return 1.0f - 2.0f * r;
}

__device__ __forceinline__ void gl_lds16(const void* g, void* l) {
    __builtin_amdgcn_global_load_lds(
        (const __attribute__((address_space(1))) void*)g,
        (__attribute__((address_space(3))) void*)l, 16, 0, 0);
}

// ---------------- merged weight prep ----------------
__global__ void prep_weights(const float* __restrict__ W1, const float* __restrict__ W2,
                             short* __restrict__ W1t, short* __restrict__ W2p) {
    __shared__ float tile[64][65];
    const int tx = threadIdx.x & 63, ty = threadIdx.x >> 6;
    const int r0 = blockIdx.y * 64, c0 = blockIdx.x * 64;
    if (blockIdx.z == 0) {
#pragma unroll
        for (int i = 0; i < 16; ++i) {
            int r = r0 + i * 4 + ty, c = c0 + tx;
            tile[i * 4 + ty][tx] = W1[(long)r * 1024 + c];
        }
        __syncthreads();
#pragma unroll
        for (int i = 0; i < 16; ++i) {
            int oc = c0 + i * 4 + ty;
            int orr = r0 + tx;
            W1t[(long)oc * WK + orr] = f2bf(tile[tx][i * 4 + ty]);
        }
    } else {
#pragma unroll
        for (int i = 0; i < 16; ++i) {
            int r = r0 + i * 4 + ty, c = c0 + tx;   // r=k, c=v
            float v = 0.f;
            if (c < V_) v = W2[(long)r * V_ + c];
            tile[i * 4 + ty][tx] = v;
        }
        __syncthreads();
#pragma unroll
        for (int i = 0; i < 16; ++i) {
            int oc = c0 + i * 4 + ty;       // v 0..1023
            int orr = r0 + tx;              // k 0..1023
            int nb = oc >> 8, prow = oc & 255, kt = orr >> 5, ks = orr & 31;
            W2p[(long)(nb * 32 + kt) * 8192 + prow * 32 + ks] = f2bf(tile[tx][i * 4 + ty]);
        }
    }
}

// ---------------- merged projections (bf16 out) ----------------
__global__ __launch_bounds__(256, 2) void proj_both(
        const float* __restrict__ enc, const float* __restrict__ dec,
        const short* __restrict__ Wt, const float* __restrict__ b1,
        short* __restrict__ encB, short* __restrict__ decB)
{
    __shared__ short As[64 * 64];
    const int tid = threadIdx.x;
    const int lane = tid & 63;
    const int w = tid >> 6;
    const int wm = w >> 1, wn = w & 1;

    const int bx = blockIdx.x;
    const bool isenc = bx < 19;
    const float* X  = isenc ? enc : dec;
    const int M     = isenc ? 1200 : 240;
    const int k_off = isenc ? 0 : 512;
    short* P        = isenc ? encB : decB;
    const int m0 = (isenc ? bx : bx - 19) * 64;
    const int n0 = blockIdx.y * 64;

    f32x4 acc[2][2] = {};
    for (int k0 = 0; k0 < 512; k0 += 64) {
#pragma unroll
        for (int c = 0; c < 2; ++c) {
            int lin = tid + 256 * c;
            int row = lin >> 3, k8 = lin & 7;
            int m = m0 + row;
            short vals[8];
            if (m < M) {
                const float* xp = X + (long)m * 512 + k0 + k8 * 8;
#pragma unroll
                for (int j = 0; j < 8; ++j) vals[j] = f2bf(xp[j]);
            } else {
#pragma unroll
                for (int j = 0; j < 8; ++j) vals[j] = 0;
            }
            int byte = row * 128 + k8 * 16;
            byte ^= (row & 7) << 4;
            *(int4v*)((char*)As + byte) = *(const int4v*)vals;
        }
        __syncthreads();
#pragma unroll
        for (int ks = 0; ks < 2; ++ks) {
            short8 af[2];
#pragma unroll
            for (int mf = 0; mf < 2; ++mf) {
                int row = wm * 32 + mf * 16 + (lane & 15);
                int byte = row * 128 + ks * 64 + (lane >> 4) * 16;
                byte ^= (row & 7) << 4;
                af[mf] = *(const short8*)((char*)As + byte);
            }
#pragma unroll
            for (int nf = 0; nf < 2; ++nf) {
                int h = n0 + wn * 32 + nf * 16 + (lane & 15);
                const short* bp = Wt + (long)h * WK + k_off + k0 + ks * 32 + (lane >> 4) * 8;
                short8 bfv = *(const short8*)bp;
#pragma unroll
                for (int mf = 0; mf < 2; ++mf)
                    acc[mf][nf] = __builtin_amdgcn_mfma_f32_16x16x32_bf16(af[mf], bfv, acc[mf][nf], 0, 0, 0);
            }
        }
        __syncthreads();
    }
#pragma unroll
    for (int mf = 0; mf < 2; ++mf)
#pragma unroll
        for (int nf = 0; nf < 2; ++nf) {
            int h = n0 + wn * 32 + nf * 16 + (lane & 15);
            float bb = isenc ? 0.f : b1[h];
#pragma unroll
            for (int j = 0; j < 4; ++j) {
                int m = m0 + wm * 32 + mf * 16 + (lane >> 4) * 4 + j;
                if (m < M) P[(long)m * 1024 + h] = f2bf(acc[mf][nf][j] + bb);
            }
        }
}

// ---------------- packed H, chunked (bf16 inputs) ----------------
// unit u_local = mbl*32+kt: 128 rows x 32 shorts (8KB); thread -> one 16B granule.
__global__ __launch_bounds__(256) void hgen_pk(
        const short* __restrict__ encB, const short* __restrict__ decB,
        short* __restrict__ Hp, int mb_base)
{
    long idx = (long)blockIdx.x * 256 + threadIdx.x;
    int u = (int)(idx >> 9);           // local unit
    int gi = (int)(idx & 511);
    int mbl = u >> 5, kt = u & 31;
    int r = gi >> 2, g = gi & 3;
    int m = (mb_base + mbl) * 128 + r;
    int k = kt * 32 + g * 8;
    short8 v = {};
    if (m < M_TOT) {
        int bt = m / U_;
        int uu = m - bt * U_;
        int b = m / (T_ * U_);
        short8 e = *(const short8*)(encB + (long)bt * 1024 + k);
        short8 d = *(const short8*)(decB + (long)(b * U_ + uu) * 1024 + k);
#pragma unroll
        for (int j = 0; j < 8; ++j)
            v[j] = f2bf(fast_tanh(b2f(e[j]) + b2f(d[j])));
    }
    *(short8*)(Hp + (long)u * 4096 + gi * 8) = v;
}

// ---------------- main GEMM (R13 gemm_pk, chunked over M) ----------
// BM=128, BN=256, wave tile 64x64 (8 waves 2m x 4n), BK=32, 32 K-tiles.
// 3-slot LDS ring (24KB/slot, 72KB) -> 2 blocks/CU. H read from the chunk
// buffer that hgen just wrote -> L3-resident (74 MB), no HBM round-trip.
__global__ __launch_bounds__(512, 4) void gemm_pk(
        const short* __restrict__ Hp,   // [mb_cnt*32 units][4096 shorts]
        const short* __restrict__ W2p,  // [4*32 units][8192 shorts]
        const float* __restrict__ b2,
        float* __restrict__ out,        // [M_TOT][V_]
        int mb_base)
{
    __shared__ __align__(16) char lds[3 * 24576];

    const int tid = threadIdx.x;
    const int lane = tid & 63;
    const int w = tid >> 6;            // 0..7
    const int wm = w >> 2, wn = w & 3; // 2m x 4n
    const int l15 = lane & 15, ksel = lane >> 4;

    const int nwg = gridDim.x;
    int bid = blockIdx.x;
    int q = nwg >> 3, r = nwg & 7;
    int xcd = bid & 7, lq = bid >> 3;
    int wg = (xcd < r ? xcd * (q + 1) : r * (q + 1) + (xcd - r) * q) + lq;
    const int mbl = wg >> 2;           // local mb
    const int nb = wg & 3;
    const int m0 = (mb_base + mbl) * 128, n0 = nb * 256;

    const int sr = tid >> 2;
    const int sg = (tid & 3) ^ ((sr >> 1) & 3);
    const short* aU = Hp + (long)mbl * 32 * 4096 + sr * 32 + sg * 8;
    const short* bU = W2p + (long)nb * 32 * 8192 + sr * 32 + sg * 8;
    char* const ldsw = (char*)lds + (w << 10);

#define STAGE_A(t_, sl_) gl_lds16(aU + (long)(t_) * 4096, ldsw + (sl_) * 24576)
#define STAGE_B(t_, sl_) do {                                               \
    char* db_ = ldsw + (sl_) * 24576 + 8192;                                \
    gl_lds16(bU + (long)(t_) * 8192, db_);                                  \
    gl_lds16(bU + (long)(t_) * 8192 + 4096, db_ + 8192);                    \
} while (0)

    f32x4 acc[4][4] = {};
    short8 af[4], bf[4];

#define PH_A(sl_, DOSTAGE, t2_, ss_) do {                                   \
    const char* Ab_ = (const char*)lds + (sl_) * 24576;                     \
    const char* Bb_ = Ab_ + 8192;                                           \
    _Pragma("unroll")                                                       \
    for (int nf = 0; nf < 2; ++nf) {                                        \
        int rw = wn * 64 + nf * 16 + l15;                                   \
        bf[nf] = *(const short8*)(Bb_ + rw * 64 + ((ksel ^ ((rw >> 1) & 3)) << 4)); \
    }                                                                       \
    _Pragma("unroll")                                                       \
    for (int mf = 0; mf < 4; ++mf) {                                        \
        int rw = wm * 64 + mf * 16 + l15;                                   \
        af[mf] = *(const short8*)(Ab_ + rw * 64 + ((ksel ^ ((rw >> 1) & 3)) << 4)); \
    }                                                                       \
    if (DOSTAGE) STAGE_A(t2_, ss_);                                         \
    __builtin_amdgcn_s_barrier();                                           \
    asm volatile("s_waitcnt lgkmcnt(0)" ::: "memory");                      \
    __builtin_amdgcn_s_setprio(1);                                          \
    _Pragma("unroll")                                                       \
    for (int nf = 0; nf < 2; ++nf)                                          \
        _Pragma("unroll")                                                   \
        for (int mf = 0; mf < 4; ++mf)                                      \
            acc[mf][nf] = __builtin_amdgcn_mfma_f32_16x16x32_bf16(          \
                af[mf], bf[nf], acc[mf][nf], 0, 0, 0);                      \
    __builtin_amdgcn_s_setprio(0);                                          \
    __builtin_amdgcn_s_barrier();                                           \
} while (0)

#define PH_B(sl_, DOSTAGE, t2_, ss_, GATE) do {                             \
    const char* Ab_ = (const char*)lds + (sl_) * 24576;                     \
    const char* Bb_ = Ab_ + 8192;                                           \
    _Pragma("unroll")                                                       \
    for (int nf = 2; nf < 4; ++nf) {                                        \
        int rw = wn * 64 + nf * 16 + l15;                                   \
        bf[nf] = *(const short8*)(Bb_ + rw * 64 + ((ksel ^ ((rw >> 1) & 3)) << 4)); \
    }                                                                       \
    if (DOSTAGE) STAGE_B(t2_, ss_);                                         \
    GATE                                                                    \
    __builtin_amdgcn_s_barrier();                                           \
    asm volatile("s_waitcnt lgkmcnt(0)" ::: "memory");                      \
    __builtin_amdgcn_s_setprio(1);                                          \
    _Pragma("unroll")                                                       \
    for (int nf = 2; nf < 4; ++nf)                                          \
        _Pragma("unroll")                                                   \
        for (int mf = 0; mf < 4; ++mf)                                      \
            acc[mf][nf] = __builtin_amdgcn_mfma_f32_16x16x32_bf16(          \
                af[mf], bf[nf], acc[mf][nf], 0, 0, 0);                      \
    __builtin_amdgcn_s_setprio(0);                                          \
    __builtin_amdgcn_s_barrier();                                           \
} while (0)

#define GATE3 asm volatile("s_waitcnt vmcnt(3)" ::: "memory");
#define GATE0 asm volatile("s_waitcnt vmcnt(0)" ::: "memory");
#define NOGATE

    STAGE_A(0, 0); STAGE_B(0, 0);
    STAGE_A(1, 1); STAGE_B(1, 1);
    asm volatile("s_waitcnt vmcnt(3)" ::: "memory");
    __builtin_amdgcn_s_barrier();

    int s = 0, ss = 2;
#pragma unroll 1
    for (int t = 0; t < 30; ++t) {
        PH_A(s, true, t + 2, ss);
        PH_B(s, true, t + 2, ss, GATE3);
        s = (s == 2) ? 0 : s + 1;
        ss = (ss == 2) ? 0 : ss + 1;
    }
    PH_A(s, false, 0, 0); PH_B(s, false, 0, 0, GATE0);
    s = (s == 2) ? 0 : s + 1;
    PH_A(s, false, 0, 0); PH_B(s, false, 0, 0, NOGATE);

#pragma unroll
    for (int nf = 0; nf < 4; ++nf) {
        int n = n0 + wn * 64 + nf * 16 + l15;
        if (n < V_) {
            float bv = b2[n];
#pragma unroll
            for (int mf = 0; mf < 4; ++mf)
#pragma unroll
                for (int j = 0; j < 4; ++j) {
                    int m = m0 + wm * 64 + mf * 16 + ksel * 4 + j;
                    if (m < M_TOT)
                        out[(long)m * V_ + n] = acc[mf][nf][j] + bv;
                }
        }
    }
#undef PH_A
#undef PH_B
#undef STAGE_A
#undef STAGE_B
#undef GATE3
#undef GATE0
#undef NOGATE
}

// ---------------- launch ----------------
extern "C" void kernel_launch(void* const* d_in, const int* in_sizes, int n_in,
                              void* d_out, int out_size, void* d_ws, size_t ws_size,
                              hipStream_t stream) {
    const float* enc = (const float*)d_in[0];
    const float* dec = (const float*)d_in[1];
    const float* W1  = (const float*)d_in[2];
    const float* b1  = (const float*)d_in[3];
    const float* W2  = (const float*)d_in[4];
    const float* b2  = (const float*)d_in[5];
    float* out = (float*)d_out;

    char* ws = (char*)d_ws;
    size_t off = 0;
    short* W1t  = (short*)(ws + off); off += (size_t)1024 * WK * 2;          // 2.06 MB
    short* W2p  = (short*)(ws + off); off += (size_t)4 * 32 * 8192 * 2;      // 2.00 MB
    short* encB = (short*)(ws + off); off += (size_t)1216 * 1024 * 2;        // 2.49 MB
    short* decB = (short*)(ws + off); off += (size_t)256 * 1024 * 2;         // 0.52 MB
    short* Hp   = (short*)(ws + off);                                        // 74 MB (reused per chunk)

    prep_weights<<<dim3(16, 16, 2), 256, 0, stream>>>(W1, W2, W1t, W2p);
    proj_both<<<dim3(23, 16), 256, 0, stream>>>(enc, dec, W1t, b1, encB, decB);

    // chunk 0: mb 0..281 ; chunk 1: mb 282..562 — H stays L3-resident
    hgen_pk<<<CH0 * 64, 256, 0, stream>>>(encB, decB, Hp, 0);
    gemm_pk<<<CH0 * 4, 512, 0, stream>>>(Hp, W2p, b2, out, 0);
    hgen_pk<<<CH1 * 64, 256, 0, stream>>>(encB, decB, Hp, CH0);
    gemm_pk<<<CH1 * 4, 512, 0, stream>>>(Hp, W2p, b2, out, CH0);
}